// Round 10
// baseline (439.024 us; speedup 1.0000x reference)
//
#include <hip/hip_runtime.h>

// ModConv2D — StyleGAN2 modulated conv as implicit GEMM, f16 MFMA.
// B=16, H=W=64, CIN=COUT=256, 3x3 SAME, fp32 I/O.
//
// R10 = R9 pipeline + PITCH-34 LDS cells (68 B; odd word-stride 17 -> all
// fragment reads/writes <=2-way bank aliased = free; R9's unpadded 64-B cells
// gave ~8-way conflicts, 1.4e7 extra cycles). LDS 54336 B -> still 3 blk/CU.
// Prep reverted to parallel tap-split scale (R8 style, fused w/ transpose).

#define HH 64
#define WW 64
#define CI 256
#define CO 256
#define PITCH 34                 // ushorts/cell: 32 data + 2 pad
#define XSW (264 * PITCH)        // 8976 ushorts per xs buffer
#define BSW (128 * PITCH)        // 4352 ushorts per bs buffer

typedef float    f32x4 __attribute__((ext_vector_type(4)));
typedef _Float16 f16x8 __attribute__((ext_vector_type(8)));
typedef __fp16   fp16x2 __attribute__((ext_vector_type(2)));

__device__ __forceinline__ unsigned pk2(float a, float b) {
    fp16x2 h = __builtin_amdgcn_cvt_pkrtz(a, b);
    return __builtin_bit_cast(unsigned, h);
}

// ---- fused prep: blk<144 = Wt2 transpose+f16; blk>=144 = demod partials ----
__global__ __launch_bounds__(256) void prep_kernel(
    const float* __restrict__ kern,    // [9][CI][CO] = [2304][256]
    const float* __restrict__ style,   // [B][CI]
    ushort* __restrict__ Wt2,          // [8][9][256 co][32 kk] f16
    float* __restrict__ scale2)        // [B][CO] sum-of-squares (pre-zeroed)
{
    const int blk = blockIdx.x;
    const int tid = threadIdx.x;
    if (blk < 144) {
        __shared__ ushort tile[64][65];
        const int kt = blk >> 2, ct = blk & 3;
        const int k0 = kt * 64, c0 = ct * 64;
        const int r = tid >> 2, q = tid & 3;
        const float* src = kern + (size_t)(k0 + r) * CO + c0 + q * 16;
        #pragma unroll
        for (int j = 0; j < 16; ++j) {
            _Float16 h = (_Float16)src[j];
            tile[q * 16 + j][r] = __builtin_bit_cast(unsigned short, h);
        }
        __syncthreads();
        const int kbase = k0 + q * 16;          // k = t*256 + ci, 16-contiguous
        const int t  = kbase >> 8;
        const int ci = kbase & 255;
        const int cs = ci >> 5, kk = ci & 31;
        ushort* dst = Wt2 + (((size_t)(cs * 9 + t) * 256 + c0 + r) * 32 + kk);
        #pragma unroll
        for (int j = 0; j < 16; ++j) dst[j] = tile[r][q * 16 + j];
    } else {
        const int bb = blk - 144;               // b*9 + t
        const int b = bb / 9;
        const int t = bb - b * 9;
        __shared__ float st[CI];
        st[tid] = style[b * CI + tid] + 1.0f;
        __syncthreads();
        float acc = 0.f;
        const float* kp = kern + (size_t)t * CI * CO + tid;
        #pragma unroll 8
        for (int ci = 0; ci < CI; ++ci) {
            float m = kp[ci * CO] * st[ci];
            acc += m * m;
        }
        atomicAdd(&scale2[b * CO + tid], acc);
    }
}

// ---- implicit-GEMM conv: 1024 blocks, 256 thr, tile 128M x 128N ----
__global__ __launch_bounds__(256, 3) void gemm_conv(
    const float* __restrict__ x,        // [B][H][W][CI] fp32
    const ushort* __restrict__ Wt2,     // [8][9][256][32] f16
    const float* __restrict__ style,    // [B][CI]
    const float* __restrict__ scale2,   // [B][CO] sum-of-squares
    float* __restrict__ y)              // [B][H][W][CO] fp32
{
    __shared__ __align__(16) ushort xs[2 * XSW];   // 35904 B
    __shared__ __align__(16) ushort bs[2 * BSW];   // 17408 B
    __shared__ float s_style[CI];                  // 1024 B

    const int tid  = threadIdx.x;
    const int lane = tid & 63;
    const int wave = tid >> 6;

    const int mtile = blockIdx.x >> 1;
    const int n0    = (blockIdx.x & 1) * 128;
    const int p0    = mtile * 128;
    const int b     = p0 >> 12;
    const int h0    = (p0 >> 6) & 63;

    s_style[tid] = style[b * CI + tid] + 1.0f;

    const int wm = (wave & 1) * 64, wn = (wave >> 1) * 64;
    const int fr = lane & 15, fq = lane >> 4;
    const int wrow = wm >> 6;

    // x-window staging units: u = g*256+tid; g<4 all threads, g==4 tid<32.
    // unit u -> cell u>>2 (row=cell/66,col=cell%66), quarter q=u&3 (8 ci).
    int  ubase[5], uq[5], uoff[5];
    bool uval[5];
    #pragma unroll
    for (int g = 0; g < 5; ++g) {
        const int u = g * 256 + tid;
        const int cell = u >> 2, q = u & 3;
        const int row = cell / 66;
        const int col = cell - 66 * row;
        const int rg = h0 - 1 + row, cg = col - 1;
        const bool act = (g < 4) || (tid < 32);
        uval[g]  = act && ((unsigned)rg < 64u) && ((unsigned)cg < 64u);
        ubase[g] = ((b * 4096 + rg * 64 + cg) << 8) + q * 8;   // f32 index sans c*32
        uq[g]    = q * 8;
        uoff[g]  = cell * PITCH + q * 8;                        // LDS ushort offset
    }

    f32x4 acc[4][4] = {};
    f32x4 rr0, rr1;        // in-flight x regs
    uint4 rb0, rb1;        // in-flight B regs

    auto xs_load = [&](int c, int g) {
        if (uval[g]) {
            const float* p = x + ubase[g] + c * 32;
            rr0 = *(const f32x4*)(p);
            rr1 = *(const f32x4*)(p + 4);
        } else {
            rr0 = (f32x4){0.f, 0.f, 0.f, 0.f};
            rr1 = rr0;
        }
    };
    auto xs_write = [&](int c, int g, int buf) {
        const bool act = (g < 4) || (tid < 32);
        if (act) {
            const f32x4 s0 = *(const f32x4*)(s_style + c * 32 + uq[g]);
            const f32x4 s1 = *(const f32x4*)(s_style + c * 32 + uq[g] + 4);
            const f32x4 m0 = rr0 * s0, m1 = rr1 * s1;
            uint4 u;
            u.x = pk2(m0.x, m0.y); u.y = pk2(m0.z, m0.w);
            u.z = pk2(m1.x, m1.y); u.w = pk2(m1.z, m1.w);
            *(uint4*)(xs + buf * XSW + uoff[g]) = u;
        }
    };
    auto bs_load = [&](int l) {
        const ushort* src = Wt2 + (size_t)l * 8192 + n0 * 32 + tid * 16;
        rb0 = *(const uint4*)(src);
        rb1 = *(const uint4*)(src + 8);
    };
    auto bs_write = [&](int l) {
        // thread covers co row tid>>1, half tid&1 (16 ushorts)
        ushort* d = bs + (l & 1) * BSW + (tid >> 1) * PITCH + (tid & 1) * 16;
        *(uint4*)(d)     = rb0;
        *(uint4*)(d + 8) = rb1;
    };

    __syncthreads();   // s_style visible before any staging reads it

    // prologue: slice 0 x-window + B chunk 0
    #pragma unroll
    for (int g = 0; g < 5; ++g) { xs_load(0, g); xs_write(0, g, 0); }
    bs_load(0); bs_write(0);
    __syncthreads();

    for (int c = 0; c < 8; ++c) {
        const ushort* xb = xs + (c & 1) * XSW;
        #pragma unroll
        for (int t = 0; t < 9; ++t) {
            const int l = c * 9 + t;
            // issue next-stage global loads FIRST (fly during MFMAs)
            if (l < 71) bs_load(l + 1);
            const bool do_xs = (c < 7) && (t < 5);
            if (do_xs) xs_load(c + 1, t);

            const int dh = t / 3, dw = t - 3 * (t / 3);
            f16x8 af[4], bf[4];
            const int arow = (wrow + dh) * 66;
            #pragma unroll
            for (int i = 0; i < 4; ++i)
                af[i] = *(const f16x8*)(xb + (arow + i * 16 + fr + dw) * PITCH + fq * 8);
            const ushort* bsb = bs + (l & 1) * BSW;
            #pragma unroll
            for (int j = 0; j < 4; ++j)
                bf[j] = *(const f16x8*)(bsb + (wn + j * 16 + fr) * PITCH + fq * 8);
            #pragma unroll
            for (int i = 0; i < 4; ++i)
                #pragma unroll
                for (int j = 0; j < 4; ++j)
                    acc[i][j] = __builtin_amdgcn_mfma_f32_16x16x32_f16(
                        af[i], bf[j], acc[i][j], 0, 0, 0);

            // drain staged data into LDS AFTER the burst, then barrier
            if (l < 71) bs_write(l + 1);
            if (do_xs) xs_write(c + 1, t, (c + 1) & 1);
            __syncthreads();
        }
    }

    // ---- epilogue: demod + store. D: col=lane&15, row=(lane>>4)*4+reg ----
    float sc[4];
    #pragma unroll
    for (int j = 0; j < 4; ++j)
        sc[j] = __frsqrt_rn(scale2[b * CO + n0 + wn + j * 16 + fr] + 1e-8f);
    #pragma unroll
    for (int i = 0; i < 4; ++i) {
        const int m_base = p0 + wm + i * 16 + fq * 4;
        #pragma unroll
        for (int j = 0; j < 4; ++j) {
            float* yp = y + (size_t)m_base * CO + n0 + wn + j * 16 + fr;
            #pragma unroll
            for (int r = 0; r < 4; ++r)
                yp[(size_t)r * CO] = acc[i][j][r] * sc[j];
        }
    }
}

extern "C" void kernel_launch(void* const* d_in, const int* in_sizes, int n_in,
                              void* d_out, int out_size, void* d_ws, size_t ws_size,
                              hipStream_t stream) {
    const float* x     = (const float*)d_in[0];  // [16,64,64,256]
    const float* style = (const float*)d_in[1];  // [16,256]
    const float* kern  = (const float*)d_in[2];  // [3,3,256,256]
    float* out = (float*)d_out;                  // [16,64,64,256]

    float*  scale2 = (float*)d_ws;                       // 16*256 fp32 = 16 KB
    ushort* Wt2    = (ushort*)((char*)d_ws + 16384);     // 72 x 16 KB f16 chunks

    hipMemsetAsync(scale2, 0, 16 * CO * sizeof(float), stream);
    prep_kernel<<<144 + 144, 256, 0, stream>>>(kern, style, Wt2, scale2);
    gemm_conv<<<1024, 256, 0, stream>>>(x, Wt2, style, scale2, out);
}